// Round 11
// baseline (5740.544 us; speedup 1.0000x reference)
//
#include <hip/hip_runtime.h>

#define N_ATOMS 2048
#define KNN 16
#define NE (N_ATOMS*KNN)   /* 32768 */
#define H 128
#define NL 10
#define NSTEPS 10
#define NCHUNK 32          /* edge chunks of 1024 for deterministic CSR build */
#define S4B ((size_t)16384)   /* u16 stride of packed K=128 layer */
#define S8B ((size_t)32768)   /* u16 stride of packed K=256 layer */

typedef unsigned short u16;
typedef __attribute__((ext_vector_type(4))) float f32x4;
typedef __attribute__((ext_vector_type(8))) short bf16x8;

// integer RTNE f32->bf16 (branchless; matches R9's bit-exact trajectory)
__device__ __forceinline__ u16 f2bf(float x){
  unsigned u = __float_as_uint(x);
  return (u16)((u + 0x7FFFu + ((u >> 16) & 1u)) >> 16);
}
__device__ __forceinline__ float bf2f(u16 v){ return __uint_as_float(((unsigned)v) << 16); }

// ============== swizzled bf16 LDS helpers (PITCH bytes per row) =========================
template<int PITCH>
__device__ __forceinline__ bf16x8 ldsB_m11(const u16* s, int e, int k){
  int byte = e*PITCH + (k<<1); byte ^= ((e&7)<<4);
  return *(const bf16x8*)((const char*)s + byte);
}
template<int PITCH>
__device__ __forceinline__ void lds_st16_m11(u16* s, int row, int k, uint4 v){
  int byte = row*PITCH + (k<<1); byte ^= ((row&7)<<4);
  *(uint4*)((char*)s + byte) = v;
}
template<int PITCH>
__device__ __forceinline__ uint4 lds_ld16_m11(const u16* s, int row, int k){
  int byte = row*PITCH + (k<<1); byte ^= ((row&7)<<4);
  return *(const uint4*)((const char*)s + byte);
}
template<int PITCH>
__device__ __forceinline__ void lds_st8_m11(u16* s, int row, int k, uint2 v){
  int byte = row*PITCH + (k<<1); byte ^= ((row&7)<<4);
  *(uint2*)((char*)s + byte) = v;
}

// ============== split-bf16 MFMA GEMM: D[n][r] += Wt[n][k] * X[r][k] =====================
// NT col-tiles x ET edge-tiles per wave. B-fragments (activations) amortized over NT.
template<int KST, int KS, int NT, int ET, int PITCH>
__device__ __forceinline__ void mfma_gemm_m11(const u16* sBh, const u16* sBl,
    const u16* __restrict__ pWh, const u16* __restrict__ pWl,
    int ksbase, int ntbase, int rowbase, int lane, f32x4 acc[NT][ET]){
  const int er = lane & 15, kg = lane >> 4;
  const size_t base = ((size_t)(ntbase*KST + ksbase)*64 + lane)*8;
  #pragma unroll
  for (int ks = 0; ks < KS; ks++){
    const int klds = ks*32 + kg*8;
    bf16x8 bh[ET], bl[ET];
    #pragma unroll
    for (int et = 0; et < ET; et++){
      bh[et] = ldsB_m11<PITCH>(sBh, rowbase + et*16 + er, klds);
      bl[et] = ldsB_m11<PITCH>(sBl, rowbase + et*16 + er, klds);
    }
    #pragma unroll
    for (int nt = 0; nt < NT; nt++){
      const size_t off = base + (size_t)(nt*KST + ks)*512;
      bf16x8 ah = *(const bf16x8*)(pWh + off);
      bf16x8 al = *(const bf16x8*)(pWl + off);
      #pragma unroll
      for (int et = 0; et < ET; et++){
        acc[nt][et] = __builtin_amdgcn_mfma_f32_16x16x32_bf16(ah, bh[et], acc[nt][et], 0, 0, 0);
        acc[nt][et] = __builtin_amdgcn_mfma_f32_16x16x32_bf16(ah, bl[et], acc[nt][et], 0, 0, 0);
        acc[nt][et] = __builtin_amdgcn_mfma_f32_16x16x32_bf16(al, bh[et], acc[nt][et], 0, 0, 0);
      }
    }
  }
}

#define CLR_M11(acc, NT, ET) { _Pragma("unroll") for (int i_=0;i_<NT;i_++){ _Pragma("unroll") for (int j_=0;j_<ET;j_++){ \
  acc[i_][j_][0]=0.f; acc[i_][j_][1]=0.f; acc[i_][j_][2]=0.f; acc[i_][j_][3]=0.f; } } }

template<int NT, int ET, int PITCH, bool RELU>
__device__ __forceinline__ void epi_lds_m11(f32x4 acc[NT][ET], u16* sh, u16* sl,
    int ntbase, int rowbase, int lane, const float* __restrict__ bias){
  const int er = lane & 15, g = lane >> 4;
  #pragma unroll
  for (int nt = 0; nt < NT; nt++){
    const int n0 = (ntbase + nt)*16 + g*4;
    f32x4 bv = *(const f32x4*)(bias + n0);
    #pragma unroll
    for (int et = 0; et < ET; et++){
      const int e = rowbase + et*16 + er;
      unsigned hw[2], lw[2];
      #pragma unroll
      for (int q = 0; q < 2; q++){
        float v0 = acc[nt][et][2*q]   + bv[2*q];
        float v1 = acc[nt][et][2*q+1] + bv[2*q+1];
        if (RELU){ v0 = fmaxf(v0, 0.f); v1 = fmaxf(v1, 0.f); }
        u16 h0 = f2bf(v0), h1 = f2bf(v1);
        u16 l0 = f2bf(v0 - bf2f(h0)), l1 = f2bf(v1 - bf2f(h1));
        hw[q] = (unsigned)h0 | ((unsigned)h1 << 16);
        lw[q] = (unsigned)l0 | ((unsigned)l1 << 16);
      }
      uint2 hv; hv.x = hw[0]; hv.y = hw[1];
      uint2 lv; lv.x = lw[0]; lv.y = lw[1];
      lds_st8_m11<PITCH>(sh, e, n0, hv);
      lds_st8_m11<PITCH>(sl, e, n0, lv);
    }
  }
}

// ============== weight pre-pack (chunked) ===============================================
__global__ __launch_bounds__(256) void pack_w_m11(const float* __restrict__ W,
    u16* __restrict__ ph, u16* __restrict__ pl, int KS, int L, int lstride, int roff){
  int idx = blockIdx.x*256 + threadIdx.x;
  int per = 8*KS*64;
  if (idx >= per*L) return;
  int l = idx / per, r = idx - l*per;
  int lane = r & 63, rest = r >> 6;
  int ks = rest % KS, nt = rest / KS;
  int n = nt*16 + (lane & 15), kb = ks*32 + (lane >> 4)*8;
  const float* src = W + (size_t)l*lstride;
  u16 h8[8], l8[8];
  #pragma unroll
  for (int j = 0; j < 8; j++){
    float v = src[(size_t)(roff + kb + j)*H + n];
    u16 h = f2bf(v);
    h8[j] = h; l8[j] = f2bf(v - bf2f(h));
  }
  size_t off = (size_t)idx*8;
  uint4 hv, lv;
  hv.x = h8[0]|((unsigned)h8[1]<<16); hv.y = h8[2]|((unsigned)h8[3]<<16);
  hv.z = h8[4]|((unsigned)h8[5]<<16); hv.w = h8[6]|((unsigned)h8[7]<<16);
  lv.x = l8[0]|((unsigned)l8[1]<<16); lv.y = l8[2]|((unsigned)l8[3]<<16);
  lv.z = l8[4]|((unsigned)l8[5]<<16); lv.w = l8[6]|((unsigned)l8[7]<<16);
  *(uint4*)(ph + off) = hv;
  *(uint4*)(pl + off) = lv;
}

// ============== fp32 LDS helpers (decode) ===============================================
__device__ __forceinline__ int lds_byte_f_m11(int r, int k4){
  return (((r<<9) + (k4<<2)) ^ (((r>>3)&7)<<4));
}
__device__ __forceinline__ f32x4 lds4r_f_m11(const float* s, int r, int k4){
  return *(const f32x4*)((const char*)s + lds_byte_f_m11(r,k4));
}
__device__ __forceinline__ void lds4w_f_m11(float* s, int r, int k4, f32x4 v){
  *(f32x4*)((char*)s + lds_byte_f_m11(r,k4)) = v;
}
__device__ __forceinline__ float lds1r_f_m11(const float* s, int r, int k){
  return *(const float*)((const char*)s + lds_byte_f_m11(r, k & ~3) + ((k&3)<<2));
}
template<int KD, int RPT>
__device__ __forceinline__ void gemm_f_m11(const float* sA, const float* __restrict__ gW,
                                           int r0, int c0, float acc[RPT][4]){
  #pragma unroll 2
  for (int k4 = 0; k4 < KD; k4 += 4){
    f32x4 a[RPT];
    #pragma unroll
    for (int i=0;i<RPT;i++) a[i] = lds4r_f_m11(sA, r0+i, k4);
    #pragma unroll
    for (int kk=0;kk<4;kk++){
      f32x4 wv = *(const f32x4*)(gW + (size_t)(k4+kk)*H + c0);
      #pragma unroll
      for (int i=0;i<RPT;i++){
        acc[i][0] = fmaf(a[i][kk], wv[0], acc[i][0]);
        acc[i][1] = fmaf(a[i][kk], wv[1], acc[i][1]);
        acc[i][2] = fmaf(a[i][kk], wv[2], acc[i][2]);
        acc[i][3] = fmaf(a[i][kk], wv[3], acc[i][3]);
      }
    }
  }
}

// ============== threefry2x32 + XLA-exact normal ========================================
__device__ __forceinline__ unsigned rotl32_m11(unsigned v, int d){ return (v << d) | (v >> (32 - d)); }
__device__ __forceinline__ void tf2x32_m11(unsigned k0, unsigned k1, unsigned x0, unsigned x1,
                                           unsigned* o0, unsigned* o1){
  unsigned ks2 = k0 ^ k1 ^ 0x1BD11BDAu;
  x0 += k0; x1 += k1;
  const int R0[4] = {13,15,26,6}, R1[4] = {17,29,16,24};
#define TFG(R) { for (int i=0;i<4;i++){ x0 += x1; x1 = rotl32_m11(x1,R[i]); x1 ^= x0; } }
  TFG(R0); x0 += k1;  x1 += ks2 + 1u;
  TFG(R1); x0 += ks2; x1 += k0  + 2u;
  TFG(R0); x0 += k0;  x1 += k1  + 3u;
  TFG(R1); x0 += k1;  x1 += ks2 + 4u;
  TFG(R0); x0 += ks2; x1 += k0  + 5u;
#undef TFG
  *o0 = x0; *o1 = x1;
}
__device__ float bits_to_normal_m11(unsigned bits){
  float f = __uint_as_float((bits >> 9) | 0x3F800000u) - 1.0f;
  const float lo = -0.99999994f;
  float u = fmaxf(lo, __fadd_rn(__fmul_rn(f, 2.0f), lo));
  float w = -log1pf(-__fmul_rn(u, u));
  float p;
  if (w < 5.0f){
    w = __fsub_rn(w, 2.5f);
    p = 2.81022636e-08f;
    p = __fadd_rn(__fmul_rn(p,w),  3.43273939e-07f);
    p = __fadd_rn(__fmul_rn(p,w), -3.5233877e-06f);
    p = __fadd_rn(__fmul_rn(p,w), -4.39150654e-06f);
    p = __fadd_rn(__fmul_rn(p,w),  0.00021858087f);
    p = __fadd_rn(__fmul_rn(p,w), -0.00125372503f);
    p = __fadd_rn(__fmul_rn(p,w), -0.00417768164f);
    p = __fadd_rn(__fmul_rn(p,w),  0.246640727f);
    p = __fadd_rn(__fmul_rn(p,w),  1.50140941f);
  } else {
    w = __fsub_rn(sqrtf(w), 3.0f);
    p = -0.000200214257f;
    p = __fadd_rn(__fmul_rn(p,w),  0.000100950558f);
    p = __fadd_rn(__fmul_rn(p,w),  0.00134934322f);
    p = __fadd_rn(__fmul_rn(p,w), -0.00367342844f);
    p = __fadd_rn(__fmul_rn(p,w),  0.00573950773f);
    p = __fadd_rn(__fmul_rn(p,w), -0.0076224613f);
    p = __fadd_rn(__fmul_rn(p,w),  0.00943887047f);
    p = __fadd_rn(__fmul_rn(p,w),  1.00167406f);
    p = __fadd_rn(__fmul_rn(p,w),  2.83297682f);
  }
  return __fmul_rn(1.41421356f, __fmul_rn(p, u));
}
__device__ __forceinline__ unsigned draw_bits_m11(unsigned k1, unsigned k2, int bk, int m, int half){
  unsigned o0, o1;
  if (bk == 0){
    if (m < half){ tf2x32_m11(k1,k2, (unsigned)m, (unsigned)(m+half), &o0,&o1); return o0; }
    else         { tf2x32_m11(k1,k2, (unsigned)(m-half), (unsigned)m, &o0,&o1); return o1; }
  }
  tf2x32_m11(k1,k2, 0u, (unsigned)m, &o0,&o1);
  return (bk==1) ? (o0^o1) : (bk==2) ? o1 : o0;
}
__global__ __launch_bounds__(64) void rng_init_m11(int* flags){
  if (threadIdx.x < 8) flags[threadIdx.x] = 1;
}
__global__ __launch_bounds__(256) void rng_detect_m11(const float* __restrict__ pos_in, int* flags){
  int m = blockIdx.x*256 + threadIdx.x;
  if (m >= N_ATOMS*3) return;
  unsigned a0,a1,b0,b1,f0,f1;
  tf2x32_m11(0u,0u, 0u,40u, &a0,&a1);
  tf2x32_m11(0u,0u, 1u,41u, &b0,&b1);
  tf2x32_m11(0u,0u, 0u,0u,  &f0,&f1);
  float target = pos_in[m];
  #pragma unroll
  for (int v = 0; v < 8; v++){
    unsigned k1 = (v<4)? a0 : f0, k2 = (v<4)? b0 : f1;
    unsigned bits = draw_bits_m11(k1,k2, v&3, m, 3072);
    float z = bits_to_normal_m11(bits);
    if (fabsf(z - target) > 1e-3f) flags[v] = 0;
  }
}
__global__ __launch_bounds__(64) void rng_select_m11(const int* flags, int* sel){
  if (threadIdx.x == 0){
    int s = -1;
    for (int v = 0; v < 8; v++) if (flags[v]){ s = v; break; }
    sel[0] = (s < 0) ? 1 : (s & 3);
  }
}
__global__ __launch_bounds__(256) void perturb_m11(const float* __restrict__ pos,
    const int* __restrict__ sel, float* __restrict__ posw, float* __restrict__ vels){
  int m = blockIdx.x*256 + threadIdx.x;
  if (m >= N_ATOMS*3) return;
  unsigned bits = draw_bits_m11(0u, 42u, sel[0], m, 3072);
  float z = bits_to_normal_m11(bits);
  posw[m] = __fadd_rn(pos[m], __fmul_rn(0.1f, z));
  vels[m] = 0.f;
}

// ============== node encoder (once) =====================================================
__global__ __launch_bounds__(128) void node_enc_m11(const float* __restrict__ nf,
    const float* __restrict__ W1, const float* __restrict__ b1,
    const float* __restrict__ W2, const float* __restrict__ b2,
    u16* __restrict__ xh, u16* __restrict__ xl){
  __shared__ float s_in[24];
  __shared__ float s_h[128];
  int n = blockIdx.x, t = threadIdx.x;
  if (t < 24) s_in[t] = nf[n*24 + t];
  __syncthreads();
  float a = b1[t];
  #pragma unroll
  for (int k = 0; k < 24; k++) a = fmaf(s_in[k], W1[k*H + t], a);
  s_h[t] = fmaxf(a, 0.f);
  __syncthreads();
  float a2 = b2[t];
  for (int k = 0; k < H; k++) a2 = fmaf(s_h[k], W2[k*H + t], a2);
  u16 h = f2bf(a2);
  xh[(size_t)n*H + t] = h;
  xl[(size_t)n*H + t] = f2bf(a2 - bf2f(h));
}

// ============== node-level P GEMM (once, layer0) ========================================
__global__ __launch_bounds__(256) void pnode_m11(
    const u16* __restrict__ xh, const u16* __restrict__ xl,
    const u16* __restrict__ pah, const u16* __restrict__ pal,
    const u16* __restrict__ pbh, const u16* __restrict__ pbl,
    float* __restrict__ P1g, float* __restrict__ P2g){
  __shared__ __align__(16) u16 sXh[16*128];
  __shared__ __align__(16) u16 sXl[16*128];
  const int t = threadIdx.x, n0b = blockIdx.x*16;
  const int i = t>>4, seg = t&15;
  {
    uint4 hv = *(const uint4*)(xh + (size_t)(n0b+i)*H + seg*8);
    uint4 lv = *(const uint4*)(xl + (size_t)(n0b+i)*H + seg*8);
    lds_st16_m11<256>(sXh, i, seg*8, hv);
    lds_st16_m11<256>(sXl, i, seg*8, lv);
  }
  __syncthreads();
  const int w = t>>6, lane = t&63, er = lane&15, g = lane>>4;
  f32x4 acc[2][1];
  CLR_M11(acc, 2, 1);
  mfma_gemm_m11<4,4,2,1,256>(sXh, sXl, pah, pal, 0, w*2, 0, lane, acc);
  #pragma unroll
  for (int nt = 0; nt < 2; nt++)
    *(f32x4*)(P1g + (size_t)(n0b+er)*H + (w*2+nt)*16 + g*4) = acc[nt][0];
  CLR_M11(acc, 2, 1);
  mfma_gemm_m11<4,4,2,1,256>(sXh, sXl, pbh, pbl, 0, w*2, 0, lane, acc);
  #pragma unroll
  for (int nt = 0; nt < 2; nt++)
    *(f32x4*)(P2g + (size_t)(n0b+er)*H + (w*2+nt)*16 + g*4) = acc[nt][0];
}

// ============== knn + ea0 + fused chunk histograms ======================================
__global__ __launch_bounds__(256) void knn_m11(const float* __restrict__ pos,
                                               int* __restrict__ senders,
                                               float* __restrict__ ea0,
                                               int* __restrict__ countsC){
  __shared__ float d2[N_ATOMS];
  __shared__ float pv[4];
  __shared__ int   pi[4];
  int r = blockIdx.x, t = threadIdx.x;
  float prx = pos[r*3+0], pry = pos[r*3+1], prz = pos[r*3+2];
  float sqr = __fadd_rn(__fadd_rn(__fmul_rn(prx,prx), __fmul_rn(pry,pry)), __fmul_rn(prz,prz));
  for (int c = t; c < N_ATOMS; c += 256){
    float cx = pos[c*3+0], cy = pos[c*3+1], cz = pos[c*3+2];
    float sqc = __fadd_rn(__fadd_rn(__fmul_rn(cx,cx), __fmul_rn(cy,cy)), __fmul_rn(cz,cz));
    float dot = __fadd_rn(__fadd_rn(__fmul_rn(prx,cx), __fmul_rn(pry,cy)), __fmul_rn(prz,cz));
    float v = __fsub_rn(__fadd_rn(sqr, sqc), __fmul_rn(2.0f, dot));
    d2[c] = (c == r) ? 1e9f : v;
  }
  __syncthreads();
  for (int j = 0; j < KNN; j++){
    float bv = 1e30f; int bi = 0x7fffffff;
    for (int c = t; c < N_ATOMS; c += 256){
      float v = d2[c];
      if (v < bv || (v == bv && c < bi)){ bv = v; bi = c; }
    }
    #pragma unroll
    for (int off = 32; off; off >>= 1){
      float ov = __shfl_down(bv, off);
      int   oi = __shfl_down(bi, off);
      if (ov < bv || (ov == bv && oi < bi)){ bv = ov; bi = oi; }
    }
    if ((t & 63) == 0){ pv[t>>6] = bv; pi[t>>6] = bi; }
    __syncthreads();
    if (t == 0){
      float fv = pv[0]; int fi = pi[0];
      #pragma unroll
      for (int q = 1; q < 4; q++){
        if (pv[q] < fv || (pv[q] == fv && pi[q] < fi)){ fv = pv[q]; fi = pi[q]; }
      }
      senders[r*KNN + j] = fi;
      atomicAdd(&countsC[(r>>6)*N_ATOMS + fi], 1);
      float dx = __fsub_rn(pos[fi*3+0], prx);
      float dy = __fsub_rn(pos[fi*3+1], pry);
      float dz = __fsub_rn(pos[fi*3+2], prz);
      float ss = __fadd_rn(__fadd_rn(__fmul_rn(dx,dx), __fmul_rn(dy,dy)), __fmul_rn(dz,dz));
      float* o = ea0 + (size_t)(r*KNN + j)*4;
      o[0] = dx; o[1] = dy; o[2] = dz; o[3] = sqrtf(ss);
      d2[fi] = 1e30f;
    }
    __syncthreads();
  }
}

// ============== CSR scan: totals -> rowstart; countsC -> per-chunk bases ================
__global__ __launch_bounds__(256) void csr_scan2_m11(int* __restrict__ countsC,
                                                     int* __restrict__ rowstart){
  __shared__ int part[256];
  const int t = threadIdx.x;
  const int base = t*8;
  int loc[8];
  int ssum = 0;
  #pragma unroll
  for (int i = 0; i < 8; i++){
    int s = base + i;
    int tv = 0;
    #pragma unroll
    for (int c = 0; c < NCHUNK; c++) tv += countsC[c*N_ATOMS + s];
    loc[i] = ssum; ssum += tv;
  }
  part[t] = ssum;
  __syncthreads();
  if (t == 0){
    int acc = 0;
    for (int i = 0; i < 256; i++){ int v = part[i]; part[i] = acc; acc += v; }
    rowstart[N_ATOMS] = acc;
  }
  __syncthreads();
  int p = part[t];
  #pragma unroll
  for (int i = 0; i < 8; i++){
    int s = base + i;
    int rs = p + loc[i];
    rowstart[s] = rs;
    int b = rs;
    #pragma unroll
    for (int c = 0; c < NCHUNK; c++){
      int tv = countsC[c*N_ATOMS + s];
      countsC[c*N_ATOMS + s] = b;
      b += tv;
    }
  }
}

// ============== CSR place: deterministic, produces elist sorted within segments =========
__global__ __launch_bounds__(1024) void csr_place_m11(const int* __restrict__ senders,
    const int* __restrict__ countsC, int* __restrict__ elist){
  __shared__ int cnt[N_ATOMS];
  __shared__ int sL[1024];
  const int c = blockIdx.x, t = threadIdx.x;
  cnt[t] = countsC[c*N_ATOMS + t];
  cnt[1024 + t] = countsC[c*N_ATOMS + 1024 + t];
  sL[t] = senders[c*1024 + t];
  __syncthreads();
  const int w = t>>6, lane = t&63, wb = w<<6;
  const int my_s = sL[t];
  int rank = 0, same = 0;
  for (int k = 0; k < 64; k++){
    int sk = sL[wb + k];
    int eq = (sk == my_s) ? 1 : 0;
    same += eq;
    if (k < lane) rank += eq;
  }
  #pragma unroll
  for (int round = 0; round < 16; round++){
    if (w == round){
      int bb = cnt[my_s];
      elist[bb + rank] = c*1024 + t;
      if (rank == same - 1) cnt[my_s] = bb + same;
    }
    __syncthreads();
  }
}

// ============== fused edge-chain (NT=4/ET=2 retile; FIRST fuses edge encoder) ===========
template<int FIRST>
__global__ __launch_bounds__(256) void chain_m11(
    const float* __restrict__ P1g, const float* __restrict__ P2g,
    u16* __restrict__ eag, const int* __restrict__ senders,
    const float* __restrict__ ea0,
    const float* __restrict__ eW1, const float* __restrict__ eb1,
    const u16* __restrict__ e2h, const u16* __restrict__ e2l, const float* __restrict__ eb2,
    const u16* __restrict__ w1h, const u16* __restrict__ w1l, const float* __restrict__ b1,
    const u16* __restrict__ w2h, const u16* __restrict__ w2l, const float* __restrict__ b2,
    const u16* __restrict__ w3h, const u16* __restrict__ w3l, const float* __restrict__ b3,
    const u16* __restrict__ w4h, const u16* __restrict__ w4l, const float* __restrict__ b4){
  __shared__ __align__(16) u16 sPh[64*128];
  __shared__ __align__(16) u16 sPl[64*128];
  __shared__ __align__(16) u16 sQh[64*128];
  __shared__ __align__(16) u16 sQl[64*128];
  __shared__ float sE0[64*4];
  const int t = threadIdx.x, e0 = blockIdx.x*64;
  const int w = t>>6, lane = t&63, er = lane&15, g = lane>>4;
  const int ntbase = (w&1)*4;        // wave col-half: cols [ntbase*16, ntbase*16+64)
  const int rowbase = (w>>1)*32;     // wave edge-half: 32 edges
  // seed acc with P1[sender] + P2[receiver]
  f32x4 acc[4][2];
  int sidx[2];
  #pragma unroll
  for (int et = 0; et < 2; et++) sidx[et] = senders[e0 + rowbase + et*16 + er];
  #pragma unroll
  for (int et = 0; et < 2; et++){
    const int rr = ((e0 + rowbase)>>4) + et;
    #pragma unroll
    for (int nt = 0; nt < 4; nt++){
      const int n0 = (ntbase+nt)*16 + g*4;
      f32x4 p1 = *(const f32x4*)(P1g + (size_t)sidx[et]*H + n0);
      f32x4 p2 = *(const f32x4*)(P2g + (size_t)rr*H + n0);
      acc[nt][et] = p1 + p2;
    }
  }
  if (FIRST){
    // fused edge encoder: ea0 -> hidden (sQ) -> MFMA e2 -> ea (sP)
    if (t < 64){
      uint4 v = *(const uint4*)(ea0 + (size_t)(e0 + t)*4);
      *(uint4*)(sE0 + t*4) = v;
    }
    __syncthreads();
    const int r0e = ((lane>>3)&7)*8, c0e = w*32 + (lane&7)*4;
    f32x4 bv1 = *(const f32x4*)(eb1 + c0e);
    f32x4 w0v = *(const f32x4*)(eW1 + 0*H + c0e);
    f32x4 w1v = *(const f32x4*)(eW1 + 1*H + c0e);
    f32x4 w2v = *(const f32x4*)(eW1 + 2*H + c0e);
    f32x4 w3v = *(const f32x4*)(eW1 + 3*H + c0e);
    #pragma unroll
    for (int i = 0; i < 8; i++){
      int rr = r0e + i;
      float e0v = sE0[rr*4+0], e1v = sE0[rr*4+1], e2v = sE0[rr*4+2], e3v = sE0[rr*4+3];
      unsigned hw[2], lw[2];
      #pragma unroll
      for (int q = 0; q < 2; q++){
        float v0 = fmaf(e3v, w3v[2*q],   fmaf(e2v, w2v[2*q],   fmaf(e1v, w1v[2*q],   fmaf(e0v, w0v[2*q],   bv1[2*q]))));
        float v1 = fmaf(e3v, w3v[2*q+1], fmaf(e2v, w2v[2*q+1], fmaf(e1v, w1v[2*q+1], fmaf(e0v, w0v[2*q+1], bv1[2*q+1]))));
        v0 = fmaxf(v0, 0.f); v1 = fmaxf(v1, 0.f);
        u16 h0 = f2bf(v0), h1 = f2bf(v1);
        u16 l0 = f2bf(v0 - bf2f(h0)), l1 = f2bf(v1 - bf2f(h1));
        hw[q] = (unsigned)h0 | ((unsigned)h1<<16);
        lw[q] = (unsigned)l0 | ((unsigned)l1<<16);
      }
      uint2 hv; hv.x = hw[0]; hv.y = hw[1];
      uint2 lv; lv.x = lw[0]; lv.y = lw[1];
      lds_st8_m11<256>(sQh, rr, c0e, hv);
      lds_st8_m11<256>(sQl, rr, c0e, lv);
    }
    __syncthreads();
    f32x4 acc0[4][2]; CLR_M11(acc0, 4, 2);
    mfma_gemm_m11<4,4,4,2,256>(sQh, sQl, e2h, e2l, 0, ntbase, rowbase, lane, acc0);
    __syncthreads();
    epi_lds_m11<4,2,256,false>(acc0, sPh, sPl, ntbase, rowbase, lane, eb2);   // ea -> sP
    __syncthreads();
  } else {
    // stage eag -> sP (contiguous 32KB block copy)
    const char* src = (const char*)(eag + (size_t)e0*256);
    #pragma unroll
    for (int m = 0; m < 8; m++){
      int byteoff = (t + m*256)*16;
      uint4 v = *(const uint4*)(src + byteoff);
      int row = byteoff>>9, off = byteoff&511;
      lds_st16_m11<256>((off<256)? sPh : sPl, row, (off&255)>>1, v);
    }
    __syncthreads();
  }
  mfma_gemm_m11<4,4,4,2,256>(sPh, sPl, w1h, w1l, 0, ntbase, rowbase, lane, acc);  // + ea@W1c
  epi_lds_m11<4,2,256,true>(acc, sQh, sQl, ntbase, rowbase, lane, b1);            // h1 -> Q
  __syncthreads();
  CLR_M11(acc, 4, 2);
  mfma_gemm_m11<4,4,4,2,256>(sQh, sQl, w2h, w2l, 0, ntbase, rowbase, lane, acc);
  epi_lds_m11<4,2,256,true>(acc, sPh, sPl, ntbase, rowbase, lane, b2);            // h2 -> P
  __syncthreads();
  CLR_M11(acc, 4, 2);
  mfma_gemm_m11<4,4,4,2,256>(sPh, sPl, w3h, w3l, 0, ntbase, rowbase, lane, acc);
  epi_lds_m11<4,2,256,true>(acc, sQh, sQl, ntbase, rowbase, lane, b3);            // h3 -> Q
  __syncthreads();
  CLR_M11(acc, 4, 2);
  mfma_gemm_m11<4,4,4,2,256>(sQh, sQl, w4h, w4l, 0, ntbase, rowbase, lane, acc);
  epi_lds_m11<4,2,256,true>(acc, sPh, sPl, ntbase, rowbase, lane, b4);            // e -> P
  __syncthreads();
  // write back: contiguous 32KB
  char* dst = (char*)(eag + (size_t)e0*256);
  #pragma unroll
  for (int m = 0; m < 8; m++){
    int byteoff = (t + m*256)*16;
    int row = byteoff>>9, off = byteoff&511;
    uint4 v = lds_ld16_m11<256>((off<256)? sPh : sPl, row, (off&255)>>1);
    *(uint4*)(dst + byteoff) = v;
  }
}

// ============== fused agg + object model: 8 nodes/block, grid 256 =======================
__global__ __launch_bounds__(256) void objagg_m11(
    const u16* __restrict__ xch, const u16* __restrict__ xcl,
    const u16* __restrict__ eag,
    const int* __restrict__ rowstart, const int* __restrict__ elist,
    const u16* __restrict__ o1h, const u16* __restrict__ o1l, const float* __restrict__ ob1,
    const u16* __restrict__ o2h, const u16* __restrict__ o2l, const float* __restrict__ ob2,
    const u16* __restrict__ nah, const u16* __restrict__ nal,
    const u16* __restrict__ nbh, const u16* __restrict__ nbl,
    u16* __restrict__ xoh, u16* __restrict__ xol,
    float* __restrict__ P1g, float* __restrict__ P2g){
  __shared__ __align__(16) u16 sIh[16*256];
  __shared__ __align__(16) u16 sIl[16*256];
  __shared__ __align__(16) u16 sHh[16*128];
  __shared__ __align__(16) u16 sHl[16*128];
  __shared__ __align__(16) u16 sXh[16*128];
  __shared__ __align__(16) u16 sXl[16*128];
  const int t = threadIdx.x, n0b = blockIdx.x*8;
  const int w = t>>6, lane = t&63;
  const int i = t>>5, c0 = (t&31)*4;
  {
    uint2 hv = *(const uint2*)(xch + (size_t)(n0b+i)*H + c0);
    uint2 lv = *(const uint2*)(xcl + (size_t)(n0b+i)*H + c0);
    lds_st8_m11<512>(sIh, i, c0, hv);
    lds_st8_m11<512>(sIl, i, c0, lv);
    float a0 = 0.f, a1 = 0.f, a2 = 0.f, a3 = 0.f;
    const int b0 = rowstart[n0b+i], e1 = rowstart[n0b+i+1];
    for (int p = b0; p < e1; p++){
      const int ed = elist[p];
      uint2 hv2 = *(const uint2*)(eag + (size_t)ed*256 + c0);
      uint2 lv2 = *(const uint2*)(eag + (size_t)ed*256 + 128 + c0);
      a0 += bf2f((u16)(hv2.x & 0xffffu)) + bf2f((u16)(lv2.x & 0xffffu));
      a1 += bf2f((u16)(hv2.x >> 16))     + bf2f((u16)(lv2.x >> 16));
      a2 += bf2f((u16)(hv2.y & 0xffffu)) + bf2f((u16)(lv2.y & 0xffffu));
      a3 += bf2f((u16)(hv2.y >> 16))     + bf2f((u16)(lv2.y >> 16));
    }
    u16 h0 = f2bf(a0), h1 = f2bf(a1), h2 = f2bf(a2), h3 = f2bf(a3);
    u16 l0 = f2bf(a0 - bf2f(h0)), l1 = f2bf(a1 - bf2f(h1));
    u16 l2 = f2bf(a2 - bf2f(h2)), l3 = f2bf(a3 - bf2f(h3));
    uint2 hvo; hvo.x = (unsigned)h0 | ((unsigned)h1<<16); hvo.y = (unsigned)h2 | ((unsigned)h3<<16);
    uint2 lvo; lvo.x = (unsigned)l0 | ((unsigned)l1<<16); lvo.y = (unsigned)l2 | ((unsigned)l3<<16);
    lds_st8_m11<512>(sIh, i, 128 + c0, hvo);
    lds_st8_m11<512>(sIl, i, 128 + c0, lvo);
  }
  __syncthreads();
  f32x4 acc[2][1];
  CLR_M11(acc, 2, 1);
  mfma_gemm_m11<8,8,2,1,512>(sIh, sIl, o1h, o1l, 0, w*2, 0, lane, acc);
  epi_lds_m11<2,1,256,true>(acc, sHh, sHl, w*2, 0, lane, ob1);
  __syncthreads();
  CLR_M11(acc, 2, 1);
  mfma_gemm_m11<4,4,2,1,256>(sHh, sHl, o2h, o2l, 0, w*2, 0, lane, acc);
  epi_lds_m11<2,1,256,false>(acc, sXh, sXl, w*2, 0, lane, ob2);
  __syncthreads();
  if (t < 128){
    int row = t>>4, seg = t&15;
    uint4 hv = lds_ld16_m11<256>(sXh, row, seg*8);
    uint4 lv = lds_ld16_m11<256>(sXl, row, seg*8);
    *(uint4*)(xoh + (size_t)(n0b+row)*H + seg*8) = hv;
    *(uint4*)(xol + (size_t)(n0b+row)*H + seg*8) = lv;
  }
  const int er = lane&15, g = lane>>4;
  CLR_M11(acc, 2, 1);
  mfma_gemm_m11<4,4,2,1,256>(sXh, sXl, nah, nal, 0, w*2, 0, lane, acc);
  if (er < 8){
    #pragma unroll
    for (int nt = 0; nt < 2; nt++)
      *(f32x4*)(P1g + (size_t)(n0b+er)*H + (w*2+nt)*16 + g*4) = acc[nt][0];
  }
  CLR_M11(acc, 2, 1);
  mfma_gemm_m11<4,4,2,1,256>(sXh, sXl, nbh, nbl, 0, w*2, 0, lane, acc);
  if (er < 8){
    #pragma unroll
    for (int nt = 0; nt < 2; nt++)
      *(f32x4*)(P2g + (size_t)(n0b+er)*H + (w*2+nt)*16 + g*4) = acc[nt][0];
  }
}

// ============== decoder + integrator ====================================================
__global__ __launch_bounds__(256) void decode_m11(
    const u16* __restrict__ xhi, const u16* __restrict__ xlo,
    const float* __restrict__ dW1, const float* __restrict__ db1,
    const float* __restrict__ dW2, const float* __restrict__ db2,
    const float* __restrict__ mass, float* __restrict__ posw, float* __restrict__ vels){
  __shared__ float sX[16*128];
  __shared__ float sY[16*128];
  const int t = threadIdx.x;
  const int n0 = blockIdx.x*16;
  const int w = t>>6, l = t&63;
  const int r0 = ((l>>3)&7)*2, c0 = w*32 + (l&7)*4;
  const int si = t>>4, sg = t&15;
  {
    const u16* ph = xhi + (size_t)(n0+si)*H + sg*8;
    const u16* pl = xlo + (size_t)(n0+si)*H + sg*8;
    uint4 hv = *(const uint4*)ph;
    uint4 lv = *(const uint4*)pl;
    unsigned hw[4] = {hv.x,hv.y,hv.z,hv.w}, lw[4] = {lv.x,lv.y,lv.z,lv.w};
    f32x4 v0, v1;
    #pragma unroll
    for (int m = 0; m < 2; m++){
      v0[2*m]   = bf2f((u16)(hw[m]&0xffffu)) + bf2f((u16)(lw[m]&0xffffu));
      v0[2*m+1] = bf2f((u16)(hw[m]>>16))     + bf2f((u16)(lw[m]>>16));
      v1[2*m]   = bf2f((u16)(hw[m+2]&0xffffu)) + bf2f((u16)(lw[m+2]&0xffffu));
      v1[2*m+1] = bf2f((u16)(hw[m+2]>>16))     + bf2f((u16)(lw[m+2]>>16));
    }
    lds4w_f_m11(sX, si, sg*8, v0);
    lds4w_f_m11(sX, si, sg*8 + 4, v1);
  }
  __syncthreads();
  float acc[2][4];
  #pragma unroll
  for (int i=0;i<2;i++){ acc[i][0]=0.f; acc[i][1]=0.f; acc[i][2]=0.f; acc[i][3]=0.f; }
  gemm_f_m11<128,2>(sX, dW1, r0, c0, acc);
  {
    f32x4 bv = *(const f32x4*)(db1 + c0);
    #pragma unroll
    for (int i=0;i<2;i++){
      f32x4 v;
      #pragma unroll
      for (int j=0;j<4;j++){ float x = acc[i][j] + bv[j]; v[j] = fmaxf(x, 0.f); }
      lds4w_f_m11(sY, r0+i, c0, v);
    }
  }
  __syncthreads();
  if (t < 48){
    int i = t/3, c = t - i*3;
    float a = db2[c];
    for (int k = 0; k < 128; k++) a = fmaf(lds1r_f_m11(sY, i, k), dW2[k*3 + c], a);
    int n = n0 + i;
    float f = a / mass[n];
    float v = vels[n*3 + c] + f;
    vels[n*3 + c] = v;
    posw[n*3 + c] += v;
  }
}

// ============== launch ==================================================================
extern "C" void kernel_launch(void* const* d_in, const int* in_sizes, int n_in,
                              void* d_out, int out_size, void* d_ws, size_t ws_size,
                              hipStream_t stream){
  const float* pos   = (const float*)d_in[0];
  const float* nodef = (const float*)d_in[1];
  const float* mass  = (const float*)d_in[2];
  const float* nW1 = (const float*)d_in[3];  const float* nb1 = (const float*)d_in[4];
  const float* nW2 = (const float*)d_in[5];  const float* nb2 = (const float*)d_in[6];
  const float* eW1 = (const float*)d_in[7];  const float* eb1 = (const float*)d_in[8];
  const float* eW2 = (const float*)d_in[9];  const float* eb2 = (const float*)d_in[10];
  const float* rmW1 = (const float*)d_in[11]; const float* rmb1 = (const float*)d_in[12];
  const float* rmW2 = (const float*)d_in[13]; const float* rmb2 = (const float*)d_in[14];
  const float* rmW3 = (const float*)d_in[15]; const float* rmb3 = (const float*)d_in[16];
  const float* rmW4 = (const float*)d_in[17]; const float* rmb4 = (const float*)d_in[18];
  const float* omW1 = (const float*)d_in[19]; const float* omb1 = (const float*)d_in[20];
  const float* omW2 = (const float*)d_in[21]; const float* omb2 = (const float*)d_in[22];
  const float* dW1 = (const float*)d_in[23]; const float* db1 = (const float*)d_in[24];
  const float* dW2 = (const float*)d_in[25]; const float* db2 = (const float*)d_in[26];

  char* wptr = (char*)d_ws;
  auto alloc = [&](size_t bytes)->void*{
    void* p = (void*)wptr; wptr += (bytes + 255) & ~(size_t)255; return p;
  };
  float* posw  = (float*)alloc((size_t)N_ATOMS*3*4);
  float* vels  = (float*)alloc((size_t)N_ATOMS*3*4);
  int*   senders = (int*)alloc((size_t)NE*4);
  float* ea0   = (float*)alloc((size_t)NE*4*4);
  u16* xench = (u16*)alloc((size_t)N_ATOMS*H*2);
  u16* xencl = (u16*)alloc((size_t)N_ATOMS*H*2);
  u16* xAh   = (u16*)alloc((size_t)N_ATOMS*H*2);
  u16* xAl   = (u16*)alloc((size_t)N_ATOMS*H*2);
  u16* xBh   = (u16*)alloc((size_t)N_ATOMS*H*2);
  u16* xBl   = (u16*)alloc((size_t)N_ATOMS*H*2);
  u16* eag   = (u16*)alloc((size_t)NE*256*2);     // 16 MB interleaved hi|lo
  float* P1g  = (float*)alloc((size_t)N_ATOMS*H*4);
  float* P2g  = (float*)alloc((size_t)N_ATOMS*H*4);
  float* P01g = (float*)alloc((size_t)N_ATOMS*H*4);
  float* P02g = (float*)alloc((size_t)N_ATOMS*H*4);
  int* rowstart = (int*)alloc((size_t)(N_ATOMS+1)*4);
  int* elist    = (int*)alloc((size_t)NE*4);
  int* countsC  = (int*)alloc((size_t)NCHUNK*N_ATOMS*4);   // 256 KB
  int* rflags   = (int*)alloc(64);
  int* rsel     = (int*)alloc(64);
  u16* p1ah = (u16*)alloc(S4B*NL*2); u16* p1al = (u16*)alloc(S4B*NL*2);
  u16* p1bh = (u16*)alloc(S4B*NL*2); u16* p1bl = (u16*)alloc(S4B*NL*2);
  u16* p1ch = (u16*)alloc(S4B*NL*2); u16* p1cl = (u16*)alloc(S4B*NL*2);
  u16* prm2h = (u16*)alloc(S4B*NL*2); u16* prm2l = (u16*)alloc(S4B*NL*2);
  u16* prm3h = (u16*)alloc(S4B*NL*2); u16* prm3l = (u16*)alloc(S4B*NL*2);
  u16* prm4h = (u16*)alloc(S4B*NL*2); u16* prm4l = (u16*)alloc(S4B*NL*2);
  u16* pom1h = (u16*)alloc(S8B*NL*2); u16* pom1l = (u16*)alloc(S8B*NL*2);
  u16* pom2h = (u16*)alloc(S4B*NL*2); u16* pom2l = (u16*)alloc(S4B*NL*2);
  u16* pe2h  = (u16*)alloc(S4B*2);    u16* pe2l  = (u16*)alloc(S4B*2);

  auto pack = [&](const float* W, u16* ph, u16* pl, int KS, int L, int lstride, int roff){
    int total = L*8*KS*64;
    pack_w_m11<<<(total+255)/256, 256, 0, stream>>>(W, ph, pl, KS, L, lstride, roff);
  };
  pack(rmW1, p1ah, p1al, 4, NL, 384*H, 0);     // W1a: x_sender rows
  pack(rmW1, p1bh, p1bl, 4, NL, 384*H, 128);   // W1b: x_receiver rows
  pack(rmW1, p1ch, p1cl, 4, NL, 384*H, 256);   // W1c: ea rows
  pack(rmW2, prm2h, prm2l, 4, NL, H*H, 0);
  pack(rmW3, prm3h, prm3l, 4, NL, H*H, 0);
  pack(rmW4, prm4h, prm4l, 4, NL, H*H, 0);
  pack(omW1, pom1h, pom1l, 8, NL, 2*H*H, 0);
  pack(omW2, pom2h, pom2l, 4, NL, H*H, 0);
  pack(eW2,  pe2h,  pe2l,  4, 1,  H*H, 0);

  rng_init_m11<<<1, 64, 0, stream>>>(rflags);
  rng_detect_m11<<<(N_ATOMS*3+255)/256, 256, 0, stream>>>(pos, rflags);
  rng_select_m11<<<1, 64, 0, stream>>>(rflags, rsel);
  perturb_m11<<<(N_ATOMS*3+255)/256, 256, 0, stream>>>(pos, rsel, posw, vels);
  node_enc_m11<<<N_ATOMS, 128, 0, stream>>>(nodef, nW1, nb1, nW2, nb2, xench, xencl);
  pnode_m11<<<N_ATOMS/16, 256, 0, stream>>>(xench, xencl, p1ah, p1al, p1bh, p1bl, P01g, P02g);

  for (int s = 0; s < NSTEPS; s++){
    hipMemsetAsync(countsC, 0, (size_t)NCHUNK*N_ATOMS*4, stream);
    knn_m11<<<N_ATOMS, 256, 0, stream>>>(posw, senders, ea0, countsC);
    csr_scan2_m11<<<1, 256, 0, stream>>>(countsC, rowstart);
    csr_place_m11<<<NCHUNK, 1024, 0, stream>>>(senders, countsC, elist);

    const u16* xch = xench; const u16* xcl = xencl;
    for (int l = 0; l < NL; l++){
      const float* Pa = (l == 0) ? P01g : P1g;
      const float* Pb = (l == 0) ? P02g : P2g;
      if (l == 0){
        chain_m11<1><<<NE/64, 256, 0, stream>>>(Pa, Pb, eag, senders,
            ea0, eW1, eb1, pe2h, pe2l, eb2,
            p1ch  + (size_t)l*S4B, p1cl  + (size_t)l*S4B, rmb1 + l*H,
            prm2h + (size_t)l*S4B, prm2l + (size_t)l*S4B, rmb2 + l*H,
            prm3h + (size_t)l*S4B, prm3l + (size_t)l*S4B, rmb3 + l*H,
            prm4h + (size_t)l*S4B, prm4l + (size_t)l*S4B, rmb4 + l*H);
      } else {
        chain_m11<0><<<NE/64, 256, 0, stream>>>(Pa, Pb, eag, senders,
            ea0, eW1, eb1, pe2h, pe2l, eb2,
            p1ch  + (size_t)l*S4B, p1cl  + (size_t)l*S4B, rmb1 + l*H,
            prm2h + (size_t)l*S4B, prm2l + (size_t)l*S4B, rmb2 + l*H,
            prm3h + (size_t)l*S4B, prm3l + (size_t)l*S4B, rmb3 + l*H,
            prm4h + (size_t)l*S4B, prm4l + (size_t)l*S4B, rmb4 + l*H);
      }
      u16* xnh = (l & 1) ? xAh : xBh;
      u16* xnl = (l & 1) ? xAl : xBl;
      int lp1 = (l < NL-1) ? (l+1) : l;
      objagg_m11<<<N_ATOMS/8, 256, 0, stream>>>(xch, xcl, eag, rowstart, elist,
          pom1h + (size_t)l*S8B, pom1l + (size_t)l*S8B, omb1 + l*H,
          pom2h + (size_t)l*S4B, pom2l + (size_t)l*S4B, omb2 + l*H,
          p1ah + (size_t)lp1*S4B, p1al + (size_t)lp1*S4B,
          p1bh + (size_t)lp1*S4B, p1bl + (size_t)lp1*S4B,
          xnh, xnl, P1g, P2g);
      xch = xnh; xcl = xnl;
    }
    decode_m11<<<N_ATOMS/16, 256, 0, stream>>>(xch, xcl, dW1, db1, dW2, db2, mass, posw, vels);
  }
  hipMemcpyAsync(d_out, posw, (size_t)N_ATOMS*3*4, hipMemcpyDeviceToDevice, stream);
}

// Round 12
// 5128.051 us; speedup vs baseline: 1.1194x; 1.1194x over previous
//
#include <hip/hip_runtime.h>

#define N_ATOMS 2048
#define KNN 16
#define NE (N_ATOMS*KNN)   /* 32768 */
#define H 128
#define NL 10
#define NSTEPS 10
#define NCHUNK 32          /* edge chunks of 1024 for deterministic CSR build */
#define S4B ((size_t)16384)   /* u16 stride of packed K=128 layer */
#define S8B ((size_t)32768)   /* u16 stride of packed K=256 layer */

typedef unsigned short u16;
typedef __attribute__((ext_vector_type(4))) float f32x4;
typedef __attribute__((ext_vector_type(8))) short bf16x8;

__device__ __forceinline__ u16 f2bf(float x){
  unsigned u = __float_as_uint(x);
  return (u16)((u + 0x7FFFu + ((u >> 16) & 1u)) >> 16);
}
__device__ __forceinline__ float bf2f(u16 v){ return __uint_as_float(((unsigned)v) << 16); }

// ============== swizzled bf16 LDS helpers (PITCH bytes per row) =========================
template<int PITCH>
__device__ __forceinline__ bf16x8 ldsB_m8(const u16* s, int e, int k){
  int byte = e*PITCH + (k<<1); byte ^= ((e&7)<<4);
  return *(const bf16x8*)((const char*)s + byte);
}
template<int PITCH>
__device__ __forceinline__ void lds_st16_m8(u16* s, int row, int k, uint4 v){
  int byte = row*PITCH + (k<<1); byte ^= ((row&7)<<4);
  *(uint4*)((char*)s + byte) = v;
}
template<int PITCH>
__device__ __forceinline__ uint4 lds_ld16_m8(const u16* s, int row, int k){
  int byte = row*PITCH + (k<<1); byte ^= ((row&7)<<4);
  return *(const uint4*)((const char*)s + byte);
}
template<int PITCH>
__device__ __forceinline__ void lds_st8_m8(u16* s, int row, int k, uint2 v){
  int byte = row*PITCH + (k<<1); byte ^= ((row&7)<<4);
  *(uint2*)((char*)s + byte) = v;
}

// ============== split-bf16 MFMA GEMM: D[n][r] += Wt[n][k] * X[r][k] =====================
template<int KST, int KS, int ET, int PITCH>
__device__ __forceinline__ void mfma_gemm_m8(const u16* sBh, const u16* sBl,
    const u16* __restrict__ pWh, const u16* __restrict__ pWl,
    int ksbase, int wpair, int rowbase, int lane, f32x4 acc[2][ET]){
  const int er = lane & 15, kg = lane >> 4;
  const size_t base = ((size_t)(wpair*KST + ksbase)*64 + lane)*8;
  #pragma unroll
  for (int ks = 0; ks < KS; ks++){
    const int klds = ks*32 + kg*8;
    bf16x8 bh[ET], bl[ET];
    #pragma unroll
    for (int et = 0; et < ET; et++){
      bh[et] = ldsB_m8<PITCH>(sBh, rowbase + et*16 + er, klds);
      bl[et] = ldsB_m8<PITCH>(sBl, rowbase + et*16 + er, klds);
    }
    #pragma unroll
    for (int nt = 0; nt < 2; nt++){
      const size_t off = base + (size_t)(nt*KST + ks)*512;
      bf16x8 ah = *(const bf16x8*)(pWh + off);
      bf16x8 al = *(const bf16x8*)(pWl + off);
      #pragma unroll
      for (int et = 0; et < ET; et++){
        acc[nt][et] = __builtin_amdgcn_mfma_f32_16x16x32_bf16(ah, bh[et], acc[nt][et], 0, 0, 0);
        acc[nt][et] = __builtin_amdgcn_mfma_f32_16x16x32_bf16(ah, bl[et], acc[nt][et], 0, 0, 0);
        acc[nt][et] = __builtin_amdgcn_mfma_f32_16x16x32_bf16(al, bh[et], acc[nt][et], 0, 0, 0);
      }
    }
  }
}

#define CLR_M8(acc, ET) { _Pragma("unroll") for (int i_=0;i_<2;i_++){ _Pragma("unroll") for (int j_=0;j_<ET;j_++){ \
  acc[i_][j_][0]=0.f; acc[i_][j_][1]=0.f; acc[i_][j_][2]=0.f; acc[i_][j_][3]=0.f; } } }

template<int ET, int PITCH, bool RELU>
__device__ __forceinline__ void epi_lds_m8(f32x4 acc[2][ET], u16* sh, u16* sl,
    int wpair, int rowbase, int lane, const float* __restrict__ bias){
  const int er = lane & 15, g = lane >> 4;
  #pragma unroll
  for (int nt = 0; nt < 2; nt++){
    const int n0 = (wpair + nt)*16 + g*4;
    f32x4 bv = *(const f32x4*)(bias + n0);
    #pragma unroll
    for (int et = 0; et < ET; et++){
      const int e = rowbase + et*16 + er;
      unsigned hw[2], lw[2];
      #pragma unroll
      for (int q = 0; q < 2; q++){
        float v0 = acc[nt][et][2*q]   + bv[2*q];
        float v1 = acc[nt][et][2*q+1] + bv[2*q+1];
        if (RELU){ v0 = fmaxf(v0, 0.f); v1 = fmaxf(v1, 0.f); }
        u16 h0 = f2bf(v0), h1 = f2bf(v1);
        u16 l0 = f2bf(v0 - bf2f(h0)), l1 = f2bf(v1 - bf2f(h1));
        hw[q] = (unsigned)h0 | ((unsigned)h1 << 16);
        lw[q] = (unsigned)l0 | ((unsigned)l1 << 16);
      }
      uint2 hv; hv.x = hw[0]; hv.y = hw[1];
      uint2 lv; lv.x = lw[0]; lv.y = lw[1];
      lds_st8_m8<PITCH>(sh, e, n0, hv);
      lds_st8_m8<PITCH>(sl, e, n0, lv);
    }
  }
}

// ============== weight pre-pack (chunked) ===============================================
__global__ __launch_bounds__(256) void pack_w_m8(const float* __restrict__ W,
    u16* __restrict__ ph, u16* __restrict__ pl, int KS, int L, int lstride, int roff){
  int idx = blockIdx.x*256 + threadIdx.x;
  int per = 8*KS*64;
  if (idx >= per*L) return;
  int l = idx / per, r = idx - l*per;
  int lane = r & 63, rest = r >> 6;
  int ks = rest % KS, nt = rest / KS;
  int n = nt*16 + (lane & 15), kb = ks*32 + (lane >> 4)*8;
  const float* src = W + (size_t)l*lstride;
  u16 h8[8], l8[8];
  #pragma unroll
  for (int j = 0; j < 8; j++){
    float v = src[(size_t)(roff + kb + j)*H + n];
    u16 h = f2bf(v);
    h8[j] = h; l8[j] = f2bf(v - bf2f(h));
  }
  size_t off = (size_t)idx*8;
  uint4 hv, lv;
  hv.x = h8[0]|((unsigned)h8[1]<<16); hv.y = h8[2]|((unsigned)h8[3]<<16);
  hv.z = h8[4]|((unsigned)h8[5]<<16); hv.w = h8[6]|((unsigned)h8[7]<<16);
  lv.x = l8[0]|((unsigned)l8[1]<<16); lv.y = l8[2]|((unsigned)l8[3]<<16);
  lv.z = l8[4]|((unsigned)l8[5]<<16); lv.w = l8[6]|((unsigned)l8[7]<<16);
  *(uint4*)(ph + off) = hv;
  *(uint4*)(pl + off) = lv;
}

// ============== fp32 LDS helpers (decode) ===============================================
__device__ __forceinline__ int lds_byte_f_m8(int r, int k4){
  return (((r<<9) + (k4<<2)) ^ (((r>>3)&7)<<4));
}
__device__ __forceinline__ f32x4 lds4r_f_m8(const float* s, int r, int k4){
  return *(const f32x4*)((const char*)s + lds_byte_f_m8(r,k4));
}
__device__ __forceinline__ void lds4w_f_m8(float* s, int r, int k4, f32x4 v){
  *(f32x4*)((char*)s + lds_byte_f_m8(r,k4)) = v;
}
__device__ __forceinline__ float lds1r_f_m8(const float* s, int r, int k){
  return *(const float*)((const char*)s + lds_byte_f_m8(r, k & ~3) + ((k&3)<<2));
}
template<int KD, int RPT>
__device__ __forceinline__ void gemm_f_m8(const float* sA, const float* __restrict__ gW,
                                          int r0, int c0, float acc[RPT][4]){
  #pragma unroll 2
  for (int k4 = 0; k4 < KD; k4 += 4){
    f32x4 a[RPT];
    #pragma unroll
    for (int i=0;i<RPT;i++) a[i] = lds4r_f_m8(sA, r0+i, k4);
    #pragma unroll
    for (int kk=0;kk<4;kk++){
      f32x4 wv = *(const f32x4*)(gW + (size_t)(k4+kk)*H + c0);
      #pragma unroll
      for (int i=0;i<RPT;i++){
        acc[i][0] = fmaf(a[i][kk], wv[0], acc[i][0]);
        acc[i][1] = fmaf(a[i][kk], wv[1], acc[i][1]);
        acc[i][2] = fmaf(a[i][kk], wv[2], acc[i][2]);
        acc[i][3] = fmaf(a[i][kk], wv[3], acc[i][3]);
      }
    }
  }
}

// ============== threefry2x32 + XLA-exact normal ========================================
__device__ __forceinline__ unsigned rotl32_m8(unsigned v, int d){ return (v << d) | (v >> (32 - d)); }
__device__ __forceinline__ void tf2x32_m8(unsigned k0, unsigned k1, unsigned x0, unsigned x1,
                                          unsigned* o0, unsigned* o1){
  unsigned ks2 = k0 ^ k1 ^ 0x1BD11BDAu;
  x0 += k0; x1 += k1;
  const int R0[4] = {13,15,26,6}, R1[4] = {17,29,16,24};
#define TFG(R) { for (int i=0;i<4;i++){ x0 += x1; x1 = rotl32_m8(x1,R[i]); x1 ^= x0; } }
  TFG(R0); x0 += k1;  x1 += ks2 + 1u;
  TFG(R1); x0 += ks2; x1 += k0  + 2u;
  TFG(R0); x0 += k0;  x1 += k1  + 3u;
  TFG(R1); x0 += k1;  x1 += ks2 + 4u;
  TFG(R0); x0 += ks2; x1 += k0  + 5u;
#undef TFG
  *o0 = x0; *o1 = x1;
}
__device__ float bits_to_normal_m8(unsigned bits){
  float f = __uint_as_float((bits >> 9) | 0x3F800000u) - 1.0f;
  const float lo = -0.99999994f;
  float u = fmaxf(lo, __fadd_rn(__fmul_rn(f, 2.0f), lo));
  float w = -log1pf(-__fmul_rn(u, u));
  float p;
  if (w < 5.0f){
    w = __fsub_rn(w, 2.5f);
    p = 2.81022636e-08f;
    p = __fadd_rn(__fmul_rn(p,w),  3.43273939e-07f);
    p = __fadd_rn(__fmul_rn(p,w), -3.5233877e-06f);
    p = __fadd_rn(__fmul_rn(p,w), -4.39150654e-06f);
    p = __fadd_rn(__fmul_rn(p,w),  0.00021858087f);
    p = __fadd_rn(__fmul_rn(p,w), -0.00125372503f);
    p = __fadd_rn(__fmul_rn(p,w), -0.00417768164f);
    p = __fadd_rn(__fmul_rn(p,w),  0.246640727f);
    p = __fadd_rn(__fmul_rn(p,w),  1.50140941f);
  } else {
    w = __fsub_rn(sqrtf(w), 3.0f);
    p = -0.000200214257f;
    p = __fadd_rn(__fmul_rn(p,w),  0.000100950558f);
    p = __fadd_rn(__fmul_rn(p,w),  0.00134934322f);
    p = __fadd_rn(__fmul_rn(p,w), -0.00367342844f);
    p = __fadd_rn(__fmul_rn(p,w),  0.00573950773f);
    p = __fadd_rn(__fmul_rn(p,w), -0.0076224613f);
    p = __fadd_rn(__fmul_rn(p,w),  0.00943887047f);
    p = __fadd_rn(__fmul_rn(p,w),  1.00167406f);
    p = __fadd_rn(__fmul_rn(p,w),  2.83297682f);
  }
  return __fmul_rn(1.41421356f, __fmul_rn(p, u));
}
__device__ __forceinline__ unsigned draw_bits_m8(unsigned k1, unsigned k2, int bk, int m, int half){
  unsigned o0, o1;
  if (bk == 0){
    if (m < half){ tf2x32_m8(k1,k2, (unsigned)m, (unsigned)(m+half), &o0,&o1); return o0; }
    else         { tf2x32_m8(k1,k2, (unsigned)(m-half), (unsigned)m, &o0,&o1); return o1; }
  }
  tf2x32_m8(k1,k2, 0u, (unsigned)m, &o0,&o1);
  return (bk==1) ? (o0^o1) : (bk==2) ? o1 : o0;
}
__global__ __launch_bounds__(64) void rng_init_m8(int* flags){
  if (threadIdx.x < 8) flags[threadIdx.x] = 1;
}
__global__ __launch_bounds__(256) void rng_detect_m8(const float* __restrict__ pos_in, int* flags){
  int m = blockIdx.x*256 + threadIdx.x;
  if (m >= N_ATOMS*3) return;
  unsigned a0,a1,b0,b1,f0,f1;
  tf2x32_m8(0u,0u, 0u,40u, &a0,&a1);
  tf2x32_m8(0u,0u, 1u,41u, &b0,&b1);
  tf2x32_m8(0u,0u, 0u,0u,  &f0,&f1);
  float target = pos_in[m];
  #pragma unroll
  for (int v = 0; v < 8; v++){
    unsigned k1 = (v<4)? a0 : f0, k2 = (v<4)? b0 : f1;
    unsigned bits = draw_bits_m8(k1,k2, v&3, m, 3072);
    float z = bits_to_normal_m8(bits);
    if (fabsf(z - target) > 1e-3f) flags[v] = 0;
  }
}
__global__ __launch_bounds__(64) void rng_select_m8(const int* flags, int* sel){
  if (threadIdx.x == 0){
    int s = -1;
    for (int v = 0; v < 8; v++) if (flags[v]){ s = v; break; }
    sel[0] = (s < 0) ? 1 : (s & 3);
  }
}
__global__ __launch_bounds__(256) void perturb_m8(const float* __restrict__ pos,
    const int* __restrict__ sel, float* __restrict__ posw, float* __restrict__ vels){
  int m = blockIdx.x*256 + threadIdx.x;
  if (m >= N_ATOMS*3) return;
  unsigned bits = draw_bits_m8(0u, 42u, sel[0], m, 3072);
  float z = bits_to_normal_m8(bits);
  posw[m] = __fadd_rn(pos[m], __fmul_rn(0.1f, z));
  vels[m] = 0.f;
}

// ============== node encoder (once) =====================================================
__global__ __launch_bounds__(128) void node_enc_m8(const float* __restrict__ nf,
    const float* __restrict__ W1, const float* __restrict__ b1,
    const float* __restrict__ W2, const float* __restrict__ b2,
    u16* __restrict__ xh, u16* __restrict__ xl){
  __shared__ float s_in[24];
  __shared__ float s_h[128];
  int n = blockIdx.x, t = threadIdx.x;
  if (t < 24) s_in[t] = nf[n*24 + t];
  __syncthreads();
  float a = b1[t];
  #pragma unroll
  for (int k = 0; k < 24; k++) a = fmaf(s_in[k], W1[k*H + t], a);
  s_h[t] = fmaxf(a, 0.f);
  __syncthreads();
  float a2 = b2[t];
  for (int k = 0; k < H; k++) a2 = fmaf(s_h[k], W2[k*H + t], a2);
  u16 h = f2bf(a2);
  xh[(size_t)n*H + t] = h;
  xl[(size_t)n*H + t] = f2bf(a2 - bf2f(h));
}

// ============== node-level P GEMM (once, layer0) ========================================
__global__ __launch_bounds__(256) void pnode_m8(
    const u16* __restrict__ xh, const u16* __restrict__ xl,
    const u16* __restrict__ pah, const u16* __restrict__ pal,
    const u16* __restrict__ pbh, const u16* __restrict__ pbl,
    float* __restrict__ P1g, float* __restrict__ P2g){
  __shared__ __align__(16) u16 sXh[16*128];
  __shared__ __align__(16) u16 sXl[16*128];
  const int t = threadIdx.x, n0b = blockIdx.x*16;
  const int i = t>>4, seg = t&15;
  {
    uint4 hv = *(const uint4*)(xh + (size_t)(n0b+i)*H + seg*8);
    uint4 lv = *(const uint4*)(xl + (size_t)(n0b+i)*H + seg*8);
    lds_st16_m8<256>(sXh, i, seg*8, hv);
    lds_st16_m8<256>(sXl, i, seg*8, lv);
  }
  __syncthreads();
  const int w = t>>6, lane = t&63, er = lane&15, g = lane>>4;
  f32x4 acc[2][1];
  CLR_M8(acc, 1);
  mfma_gemm_m8<4,4,1,256>(sXh, sXl, pah, pal, 0, w*2, 0, lane, acc);
  #pragma unroll
  for (int nt = 0; nt < 2; nt++)
    *(f32x4*)(P1g + (size_t)(n0b+er)*H + (w*2+nt)*16 + g*4) = acc[nt][0];
  CLR_M8(acc, 1);
  mfma_gemm_m8<4,4,1,256>(sXh, sXl, pbh, pbl, 0, w*2, 0, lane, acc);
  #pragma unroll
  for (int nt = 0; nt < 2; nt++)
    *(f32x4*)(P2g + (size_t)(n0b+er)*H + (w*2+nt)*16 + g*4) = acc[nt][0];
}

// ============== knn + ea0 + fused chunk histograms ======================================
__global__ __launch_bounds__(256) void knn_m9(const float* __restrict__ pos,
                                              int* __restrict__ senders,
                                              float* __restrict__ ea0,
                                              int* __restrict__ countsC){
  __shared__ float d2[N_ATOMS];
  __shared__ float pv[4];
  __shared__ int   pi[4];
  int r = blockIdx.x, t = threadIdx.x;
  float prx = pos[r*3+0], pry = pos[r*3+1], prz = pos[r*3+2];
  float sqr = __fadd_rn(__fadd_rn(__fmul_rn(prx,prx), __fmul_rn(pry,pry)), __fmul_rn(prz,prz));
  for (int c = t; c < N_ATOMS; c += 256){
    float cx = pos[c*3+0], cy = pos[c*3+1], cz = pos[c*3+2];
    float sqc = __fadd_rn(__fadd_rn(__fmul_rn(cx,cx), __fmul_rn(cy,cy)), __fmul_rn(cz,cz));
    float dot = __fadd_rn(__fadd_rn(__fmul_rn(prx,cx), __fmul_rn(pry,cy)), __fmul_rn(prz,cz));
    float v = __fsub_rn(__fadd_rn(sqr, sqc), __fmul_rn(2.0f, dot));
    d2[c] = (c == r) ? 1e9f : v;
  }
  __syncthreads();
  for (int j = 0; j < KNN; j++){
    float bv = 1e30f; int bi = 0x7fffffff;
    for (int c = t; c < N_ATOMS; c += 256){
      float v = d2[c];
      if (v < bv || (v == bv && c < bi)){ bv = v; bi = c; }
    }
    #pragma unroll
    for (int off = 32; off; off >>= 1){
      float ov = __shfl_down(bv, off);
      int   oi = __shfl_down(bi, off);
      if (ov < bv || (ov == bv && oi < bi)){ bv = ov; bi = oi; }
    }
    if ((t & 63) == 0){ pv[t>>6] = bv; pi[t>>6] = bi; }
    __syncthreads();
    if (t == 0){
      float fv = pv[0]; int fi = pi[0];
      #pragma unroll
      for (int q = 1; q < 4; q++){
        if (pv[q] < fv || (pv[q] == fv && pi[q] < fi)){ fv = pv[q]; fi = pi[q]; }
      }
      senders[r*KNN + j] = fi;
      atomicAdd(&countsC[(r>>6)*N_ATOMS + fi], 1);
      float dx = __fsub_rn(pos[fi*3+0], prx);
      float dy = __fsub_rn(pos[fi*3+1], pry);
      float dz = __fsub_rn(pos[fi*3+2], prz);
      float ss = __fadd_rn(__fadd_rn(__fmul_rn(dx,dx), __fmul_rn(dy,dy)), __fmul_rn(dz,dz));
      float* o = ea0 + (size_t)(r*KNN + j)*4;
      o[0] = dx; o[1] = dy; o[2] = dz; o[3] = sqrtf(ss);
      d2[fi] = 1e30f;
    }
    __syncthreads();
  }
}

// ============== CSR scan: totals -> rowstart; countsC -> per-chunk bases ================
__global__ __launch_bounds__(256) void csr_scan2_m9(int* __restrict__ countsC,
                                                    int* __restrict__ rowstart){
  __shared__ int part[256];
  const int t = threadIdx.x;
  const int base = t*8;
  int loc[8];
  int ssum = 0;
  #pragma unroll
  for (int i = 0; i < 8; i++){
    int s = base + i;
    int tv = 0;
    #pragma unroll
    for (int c = 0; c < NCHUNK; c++) tv += countsC[c*N_ATOMS + s];
    loc[i] = ssum; ssum += tv;
  }
  part[t] = ssum;
  __syncthreads();
  if (t == 0){
    int acc = 0;
    for (int i = 0; i < 256; i++){ int v = part[i]; part[i] = acc; acc += v; }
    rowstart[N_ATOMS] = acc;
  }
  __syncthreads();
  int p = part[t];
  #pragma unroll
  for (int i = 0; i < 8; i++){
    int s = base + i;
    int rs = p + loc[i];
    rowstart[s] = rs;
    int b = rs;
    #pragma unroll
    for (int c = 0; c < NCHUNK; c++){
      int tv = countsC[c*N_ATOMS + s];
      countsC[c*N_ATOMS + s] = b;
      b += tv;
    }
  }
}

// ============== CSR place: deterministic, produces elist sorted within segments =========
__global__ __launch_bounds__(1024) void csr_place_m9(const int* __restrict__ senders,
    const int* __restrict__ countsC, int* __restrict__ elist){
  __shared__ int cnt[N_ATOMS];
  __shared__ int sL[1024];
  const int c = blockIdx.x, t = threadIdx.x;
  cnt[t] = countsC[c*N_ATOMS + t];
  cnt[1024 + t] = countsC[c*N_ATOMS + 1024 + t];
  sL[t] = senders[c*1024 + t];
  __syncthreads();
  const int w = t>>6, lane = t&63, wb = w<<6;
  const int my_s = sL[t];
  int rank = 0, same = 0;
  for (int k = 0; k < 64; k++){
    int sk = sL[wb + k];
    int eq = (sk == my_s) ? 1 : 0;
    same += eq;
    if (k < lane) rank += eq;
  }
  #pragma unroll
  for (int round = 0; round < 16; round++){
    if (w == round){
      int bb = cnt[my_s];
      elist[bb + rank] = c*1024 + t;
      if (rank == same - 1) cnt[my_s] = bb + same;
    }
    __syncthreads();
  }
}

// ============== fused edge-chain (template FIRST fuses edge encoder) ====================
template<int FIRST>
__global__ __launch_bounds__(256) void chain_m8(
    const float* __restrict__ P1g, const float* __restrict__ P2g,
    u16* __restrict__ eag, const int* __restrict__ senders,
    const float* __restrict__ ea0,
    const float* __restrict__ eW1, const float* __restrict__ eb1,
    const u16* __restrict__ e2h, const u16* __restrict__ e2l, const float* __restrict__ eb2,
    const u16* __restrict__ w1h, const u16* __restrict__ w1l, const float* __restrict__ b1,
    const u16* __restrict__ w2h, const u16* __restrict__ w2l, const float* __restrict__ b2,
    const u16* __restrict__ w3h, const u16* __restrict__ w3l, const float* __restrict__ b3,
    const u16* __restrict__ w4h, const u16* __restrict__ w4l, const float* __restrict__ b4){
  __shared__ __align__(16) u16 sPh[64*128];
  __shared__ __align__(16) u16 sPl[64*128];
  __shared__ __align__(16) u16 sQh[64*128];
  __shared__ __align__(16) u16 sQl[64*128];
  __shared__ float sE0[64*4];
  const int t = threadIdx.x, e0 = blockIdx.x*64;
  const int w = t>>6, lane = t&63, er = lane&15, g = lane>>4;
  const int wpair = w*2;
  // seed acc with P1[sender] + P2[receiver]
  f32x4 acc[2][4];
  int sidx[4];
  #pragma unroll
  for (int et = 0; et < 4; et++) sidx[et] = senders[e0 + et*16 + er];
  #pragma unroll
  for (int et = 0; et < 4; et++){
    const int rr = (e0>>4) + et;
    #pragma unroll
    for (int nt = 0; nt < 2; nt++){
      const int n0 = (wpair+nt)*16 + g*4;
      f32x4 p1 = *(const f32x4*)(P1g + (size_t)sidx[et]*H + n0);
      f32x4 p2 = *(const f32x4*)(P2g + (size_t)rr*H + n0);
      acc[nt][et] = p1 + p2;
    }
  }
  if (FIRST){
    // fused edge encoder: ea0 -> hidden (sQ) -> MFMA e2 -> ea (sP)
    if (t < 64){
      uint4 v = *(const uint4*)(ea0 + (size_t)(e0 + t)*4);
      *(uint4*)(sE0 + t*4) = v;
    }
    __syncthreads();
    const int r0e = ((lane>>3)&7)*8, c0e = w*32 + (lane&7)*4;
    f32x4 bv1 = *(const f32x4*)(eb1 + c0e);
    f32x4 w0v = *(const f32x4*)(eW1 + 0*H + c0e);
    f32x4 w1v = *(const f32x4*)(eW1 + 1*H + c0e);
    f32x4 w2v = *(const f32x4*)(eW1 + 2*H + c0e);
    f32x4 w3v = *(const f32x4*)(eW1 + 3*H + c0e);
    #pragma unroll
    for (int i = 0; i < 8; i++){
      int rr = r0e + i;
      float e0v = sE0[rr*4+0], e1v = sE0[rr*4+1], e2v = sE0[rr*4+2], e3v = sE0[rr*4+3];
      unsigned hw[2], lw[2];
      #pragma unroll
      for (int q = 0; q < 2; q++){
        float v0 = fmaf(e3v, w3v[2*q],   fmaf(e2v, w2v[2*q],   fmaf(e1v, w1v[2*q],   fmaf(e0v, w0v[2*q],   bv1[2*q]))));
        float v1 = fmaf(e3v, w3v[2*q+1], fmaf(e2v, w2v[2*q+1], fmaf(e1v, w1v[2*q+1], fmaf(e0v, w0v[2*q+1], bv1[2*q+1]))));
        v0 = fmaxf(v0, 0.f); v1 = fmaxf(v1, 0.f);
        u16 h0 = f2bf(v0), h1 = f2bf(v1);
        u16 l0 = f2bf(v0 - bf2f(h0)), l1 = f2bf(v1 - bf2f(h1));
        hw[q] = (unsigned)h0 | ((unsigned)h1<<16);
        lw[q] = (unsigned)l0 | ((unsigned)l1<<16);
      }
      uint2 hv; hv.x = hw[0]; hv.y = hw[1];
      uint2 lv; lv.x = lw[0]; lv.y = lw[1];
      lds_st8_m8<256>(sQh, rr, c0e, hv);
      lds_st8_m8<256>(sQl, rr, c0e, lv);
    }
    __syncthreads();
    f32x4 acc0[2][4]; CLR_M8(acc0, 4);
    mfma_gemm_m8<4,4,4,256>(sQh, sQl, e2h, e2l, 0, wpair, 0, lane, acc0);
    __syncthreads();
    epi_lds_m8<4,256,false>(acc0, sPh, sPl, wpair, 0, lane, eb2);   // ea -> sP
    __syncthreads();
  } else {
    // stage eag -> sP (contiguous 32KB block copy)
    const char* src = (const char*)(eag + (size_t)e0*256);
    #pragma unroll
    for (int m = 0; m < 8; m++){
      int byteoff = (t + m*256)*16;
      uint4 v = *(const uint4*)(src + byteoff);
      int row = byteoff>>9, off = byteoff&511;
      lds_st16_m8<256>((off<256)? sPh : sPl, row, (off&255)>>1, v);
    }
    __syncthreads();
  }
  mfma_gemm_m8<4,4,4,256>(sPh, sPl, w1h, w1l, 0, wpair, 0, lane, acc);  // + ea@W1c
  epi_lds_m8<4,256,true>(acc, sQh, sQl, wpair, 0, lane, b1);            // h1 -> Q
  __syncthreads();
  CLR_M8(acc, 4);
  mfma_gemm_m8<4,4,4,256>(sQh, sQl, w2h, w2l, 0, wpair, 0, lane, acc);
  epi_lds_m8<4,256,true>(acc, sPh, sPl, wpair, 0, lane, b2);            // h2 -> P
  __syncthreads();
  CLR_M8(acc, 4);
  mfma_gemm_m8<4,4,4,256>(sPh, sPl, w3h, w3l, 0, wpair, 0, lane, acc);
  epi_lds_m8<4,256,true>(acc, sQh, sQl, wpair, 0, lane, b3);            // h3 -> Q
  __syncthreads();
  CLR_M8(acc, 4);
  mfma_gemm_m8<4,4,4,256>(sQh, sQl, w4h, w4l, 0, wpair, 0, lane, acc);
  epi_lds_m8<4,256,true>(acc, sPh, sPl, wpair, 0, lane, b4);            // e -> P
  __syncthreads();
  // write back: contiguous 32KB
  char* dst = (char*)(eag + (size_t)e0*256);
  #pragma unroll
  for (int m = 0; m < 8; m++){
    int byteoff = (t + m*256)*16;
    int row = byteoff>>9, off = byteoff&511;
    uint4 v = lds_ld16_m8<256>((off<256)? sPh : sPl, row, (off&255)>>1);
    *(uint4*)(dst + byteoff) = v;
  }
}

// ============== fused agg + object model: 8 nodes/block, grid 256 =======================
__global__ __launch_bounds__(256) void objagg_m8(
    const u16* __restrict__ xch, const u16* __restrict__ xcl,
    const u16* __restrict__ eag,
    const int* __restrict__ rowstart, const int* __restrict__ elist,
    const u16* __restrict__ o1h, const u16* __restrict__ o1l, const float* __restrict__ ob1,
    const u16* __restrict__ o2h, const u16* __restrict__ o2l, const float* __restrict__ ob2,
    const u16* __restrict__ nah, const u16* __restrict__ nal,
    const u16* __restrict__ nbh, const u16* __restrict__ nbl,
    u16* __restrict__ xoh, u16* __restrict__ xol,
    float* __restrict__ P1g, float* __restrict__ P2g){
  __shared__ __align__(16) u16 sIh[16*256];
  __shared__ __align__(16) u16 sIl[16*256];
  __shared__ __align__(16) u16 sHh[16*128];
  __shared__ __align__(16) u16 sHl[16*128];
  __shared__ __align__(16) u16 sXh[16*128];
  __shared__ __align__(16) u16 sXl[16*128];
  const int t = threadIdx.x, n0b = blockIdx.x*8;
  const int w = t>>6, lane = t&63;
  const int i = t>>5, c0 = (t&31)*4;
  {
    uint2 hv = *(const uint2*)(xch + (size_t)(n0b+i)*H + c0);
    uint2 lv = *(const uint2*)(xcl + (size_t)(n0b+i)*H + c0);
    lds_st8_m8<512>(sIh, i, c0, hv);
    lds_st8_m8<512>(sIl, i, c0, lv);
    float a0 = 0.f, a1 = 0.f, a2 = 0.f, a3 = 0.f;
    const int b0 = rowstart[n0b+i], e1 = rowstart[n0b+i+1];
    for (int p = b0; p < e1; p++){
      const int ed = elist[p];
      uint2 hv2 = *(const uint2*)(eag + (size_t)ed*256 + c0);
      uint2 lv2 = *(const uint2*)(eag + (size_t)ed*256 + 128 + c0);
      a0 += bf2f((u16)(hv2.x & 0xffffu)) + bf2f((u16)(lv2.x & 0xffffu));
      a1 += bf2f((u16)(hv2.x >> 16))     + bf2f((u16)(lv2.x >> 16));
      a2 += bf2f((u16)(hv2.y & 0xffffu)) + bf2f((u16)(lv2.y & 0xffffu));
      a3 += bf2f((u16)(hv2.y >> 16))     + bf2f((u16)(lv2.y >> 16));
    }
    u16 h0 = f2bf(a0), h1 = f2bf(a1), h2 = f2bf(a2), h3 = f2bf(a3);
    u16 l0 = f2bf(a0 - bf2f(h0)), l1 = f2bf(a1 - bf2f(h1));
    u16 l2 = f2bf(a2 - bf2f(h2)), l3 = f2bf(a3 - bf2f(h3));
    uint2 hvo; hvo.x = (unsigned)h0 | ((unsigned)h1<<16); hvo.y = (unsigned)h2 | ((unsigned)h3<<16);
    uint2 lvo; lvo.x = (unsigned)l0 | ((unsigned)l1<<16); lvo.y = (unsigned)l2 | ((unsigned)l3<<16);
    lds_st8_m8<512>(sIh, i, 128 + c0, hvo);
    lds_st8_m8<512>(sIl, i, 128 + c0, lvo);
  }
  __syncthreads();
  f32x4 acc[2][1];
  CLR_M8(acc, 1);
  mfma_gemm_m8<8,8,1,512>(sIh, sIl, o1h, o1l, 0, w*2, 0, lane, acc);
  epi_lds_m8<1,256,true>(acc, sHh, sHl, w*2, 0, lane, ob1);
  __syncthreads();
  CLR_M8(acc, 1);
  mfma_gemm_m8<4,4,1,256>(sHh, sHl, o2h, o2l, 0, w*2, 0, lane, acc);
  epi_lds_m8<1,256,false>(acc, sXh, sXl, w*2, 0, lane, ob2);
  __syncthreads();
  if (t < 128){
    int row = t>>4, seg = t&15;
    uint4 hv = lds_ld16_m8<256>(sXh, row, seg*8);
    uint4 lv = lds_ld16_m8<256>(sXl, row, seg*8);
    *(uint4*)(xoh + (size_t)(n0b+row)*H + seg*8) = hv;
    *(uint4*)(xol + (size_t)(n0b+row)*H + seg*8) = lv;
  }
  const int er = lane&15, g = lane>>4;
  CLR_M8(acc, 1);
  mfma_gemm_m8<4,4,1,256>(sXh, sXl, nah, nal, 0, w*2, 0, lane, acc);
  if (er < 8){
    #pragma unroll
    for (int nt = 0; nt < 2; nt++)
      *(f32x4*)(P1g + (size_t)(n0b+er)*H + (w*2+nt)*16 + g*4) = acc[nt][0];
  }
  CLR_M8(acc, 1);
  mfma_gemm_m8<4,4,1,256>(sXh, sXl, nbh, nbl, 0, w*2, 0, lane, acc);
  if (er < 8){
    #pragma unroll
    for (int nt = 0; nt < 2; nt++)
      *(f32x4*)(P2g + (size_t)(n0b+er)*H + (w*2+nt)*16 + g*4) = acc[nt][0];
  }
}

// ============== decoder + integrator ====================================================
__global__ __launch_bounds__(256) void decode_m8(
    const u16* __restrict__ xhi, const u16* __restrict__ xlo,
    const float* __restrict__ dW1, const float* __restrict__ db1,
    const float* __restrict__ dW2, const float* __restrict__ db2,
    const float* __restrict__ mass, float* __restrict__ posw, float* __restrict__ vels){
  __shared__ float sX[16*128];
  __shared__ float sY[16*128];
  const int t = threadIdx.x;
  const int n0 = blockIdx.x*16;
  const int w = t>>6, l = t&63;
  const int r0 = ((l>>3)&7)*2, c0 = w*32 + (l&7)*4;
  const int si = t>>4, sg = t&15;
  {
    const u16* ph = xhi + (size_t)(n0+si)*H + sg*8;
    const u16* pl = xlo + (size_t)(n0+si)*H + sg*8;
    uint4 hv = *(const uint4*)ph;
    uint4 lv = *(const uint4*)pl;
    unsigned hw[4] = {hv.x,hv.y,hv.z,hv.w}, lw[4] = {lv.x,lv.y,lv.z,lv.w};
    f32x4 v0, v1;
    #pragma unroll
    for (int m = 0; m < 2; m++){
      v0[2*m]   = bf2f((u16)(hw[m]&0xffffu)) + bf2f((u16)(lw[m]&0xffffu));
      v0[2*m+1] = bf2f((u16)(hw[m]>>16))     + bf2f((u16)(lw[m]>>16));
      v1[2*m]   = bf2f((u16)(hw[m+2]&0xffffu)) + bf2f((u16)(lw[m+2]&0xffffu));
      v1[2*m+1] = bf2f((u16)(hw[m+2]>>16))     + bf2f((u16)(lw[m+2]>>16));
    }
    lds4w_f_m8(sX, si, sg*8, v0);
    lds4w_f_m8(sX, si, sg*8 + 4, v1);
  }
  __syncthreads();
  float acc[2][4];
  #pragma unroll
  for (int i=0;i<2;i++){ acc[i][0]=0.f; acc[i][1]=0.f; acc[i][2]=0.f; acc[i][3]=0.f; }
  gemm_f_m8<128,2>(sX, dW1, r0, c0, acc);
  {
    f32x4 bv = *(const f32x4*)(db1 + c0);
    #pragma unroll
    for (int i=0;i<2;i++){
      f32x4 v;
      #pragma unroll
      for (int j=0;j<4;j++){ float x = acc[i][j] + bv[j]; v[j] = fmaxf(x, 0.f); }
      lds4w_f_m8(sY, r0+i, c0, v);
    }
  }
  __syncthreads();
  if (t < 48){
    int i = t/3, c = t - i*3;
    float a = db2[c];
    for (int k = 0; k < 128; k++) a = fmaf(lds1r_f_m8(sY, i, k), dW2[k*3 + c], a);
    int n = n0 + i;
    float f = a / mass[n];
    float v = vels[n*3 + c] + f;
    vels[n*3 + c] = v;
    posw[n*3 + c] += v;
  }
}

// ============== launch ==================================================================
extern "C" void kernel_launch(void* const* d_in, const int* in_sizes, int n_in,
                              void* d_out, int out_size, void* d_ws, size_t ws_size,
                              hipStream_t stream){
  const float* pos   = (const float*)d_in[0];
  const float* nodef = (const float*)d_in[1];
  const float* mass  = (const float*)d_in[2];
  const float* nW1 = (const float*)d_in[3];  const float* nb1 = (const float*)d_in[4];
  const float* nW2 = (const float*)d_in[5];  const float* nb2 = (const float*)d_in[6];
  const float* eW1 = (const float*)d_in[7];  const float* eb1 = (const float*)d_in[8];
  const float* eW2 = (const float*)d_in[9];  const float* eb2 = (const float*)d_in[10];
  const float* rmW1 = (const float*)d_in[11]; const float* rmb1 = (const float*)d_in[12];
  const float* rmW2 = (const float*)d_in[13]; const float* rmb2 = (const float*)d_in[14];
  const float* rmW3 = (const float*)d_in[15]; const float* rmb3 = (const float*)d_in[16];
  const float* rmW4 = (const float*)d_in[17]; const float* rmb4 = (const float*)d_in[18];
  const float* omW1 = (const float*)d_in[19]; const float* omb1 = (const float*)d_in[20];
  const float* omW2 = (const float*)d_in[21]; const float* omb2 = (const float*)d_in[22];
  const float* dW1 = (const float*)d_in[23]; const float* db1 = (const float*)d_in[24];
  const float* dW2 = (const float*)d_in[25]; const float* db2 = (const float*)d_in[26];

  char* wptr = (char*)d_ws;
  auto alloc = [&](size_t bytes)->void*{
    void* p = (void*)wptr; wptr += (bytes + 255) & ~(size_t)255; return p;
  };
  float* posw  = (float*)alloc((size_t)N_ATOMS*3*4);
  float* vels  = (float*)alloc((size_t)N_ATOMS*3*4);
  int*   senders = (int*)alloc((size_t)NE*4);
  float* ea0   = (float*)alloc((size_t)NE*4*4);
  u16* xench = (u16*)alloc((size_t)N_ATOMS*H*2);
  u16* xencl = (u16*)alloc((size_t)N_ATOMS*H*2);
  u16* xAh   = (u16*)alloc((size_t)N_ATOMS*H*2);
  u16* xAl   = (u16*)alloc((size_t)N_ATOMS*H*2);
  u16* xBh   = (u16*)alloc((size_t)N_ATOMS*H*2);
  u16* xBl   = (u16*)alloc((size_t)N_ATOMS*H*2);
  u16* eag   = (u16*)alloc((size_t)NE*256*2);     // 16 MB interleaved hi|lo
  float* P1g  = (float*)alloc((size_t)N_ATOMS*H*4);
  float* P2g  = (float*)alloc((size_t)N_ATOMS*H*4);
  float* P01g = (float*)alloc((size_t)N_ATOMS*H*4);
  float* P02g = (float*)alloc((size_t)N_ATOMS*H*4);
  int* rowstart = (int*)alloc((size_t)(N_ATOMS+1)*4);
  int* elist    = (int*)alloc((size_t)NE*4);
  int* countsC  = (int*)alloc((size_t)NCHUNK*N_ATOMS*4);   // 256 KB
  int* rflags   = (int*)alloc(64);
  int* rsel     = (int*)alloc(64);
  u16* p1ah = (u16*)alloc(S4B*NL*2); u16* p1al = (u16*)alloc(S4B*NL*2);
  u16* p1bh = (u16*)alloc(S4B*NL*2); u16* p1bl = (u16*)alloc(S4B*NL*2);
  u16* p1ch = (u16*)alloc(S4B*NL*2); u16* p1cl = (u16*)alloc(S4B*NL*2);
  u16* prm2h = (u16*)alloc(S4B*NL*2); u16* prm2l = (u16*)alloc(S4B*NL*2);
  u16* prm3h = (u16*)alloc(S4B*NL*2); u16* prm3l = (u16*)alloc(S4B*NL*2);
  u16* prm4h = (u16*)alloc(S4B*NL*2); u16* prm4l = (u16*)alloc(S4B*NL*2);
  u16* pom1h = (u16*)alloc(S8B*NL*2); u16* pom1l = (u16*)alloc(S8B*NL*2);
  u16* pom2h = (u16*)alloc(S4B*NL*2); u16* pom2l = (u16*)alloc(S4B*NL*2);
  u16* pe2h  = (u16*)alloc(S4B*2);    u16* pe2l  = (u16*)alloc(S4B*2);

  auto pack = [&](const float* W, u16* ph, u16* pl, int KS, int L, int lstride, int roff){
    int total = L*8*KS*64;
    pack_w_m8<<<(total+255)/256, 256, 0, stream>>>(W, ph, pl, KS, L, lstride, roff);
  };
  pack(rmW1, p1ah, p1al, 4, NL, 384*H, 0);     // W1a: x_sender rows
  pack(rmW1, p1bh, p1bl, 4, NL, 384*H, 128);   // W1b: x_receiver rows
  pack(rmW1, p1ch, p1cl, 4, NL, 384*H, 256);   // W1c: ea rows
  pack(rmW2, prm2h, prm2l, 4, NL, H*H, 0);
  pack(rmW3, prm3h, prm3l, 4, NL, H*H, 0);
  pack(rmW4, prm4h, prm4l, 4, NL, H*H, 0);
  pack(omW1, pom1h, pom1l, 8, NL, 2*H*H, 0);
  pack(omW2, pom2h, pom2l, 4, NL, H*H, 0);
  pack(eW2,  pe2h,  pe2l,  4, 1,  H*H, 0);

  rng_init_m8<<<1, 64, 0, stream>>>(rflags);
  rng_detect_m8<<<(N_ATOMS*3+255)/256, 256, 0, stream>>>(pos, rflags);
  rng_select_m8<<<1, 64, 0, stream>>>(rflags, rsel);
  perturb_m8<<<(N_ATOMS*3+255)/256, 256, 0, stream>>>(pos, rsel, posw, vels);
  node_enc_m8<<<N_ATOMS, 128, 0, stream>>>(nodef, nW1, nb1, nW2, nb2, xench, xencl);
  pnode_m8<<<N_ATOMS/16, 256, 0, stream>>>(xench, xencl, p1ah, p1al, p1bh, p1bl, P01g, P02g);

  for (int s = 0; s < NSTEPS; s++){
    hipMemsetAsync(countsC, 0, (size_t)NCHUNK*N_ATOMS*4, stream);
    knn_m9<<<N_ATOMS, 256, 0, stream>>>(posw, senders, ea0, countsC);
    csr_scan2_m9<<<1, 256, 0, stream>>>(countsC, rowstart);
    csr_place_m9<<<NCHUNK, 1024, 0, stream>>>(senders, countsC, elist);

    const u16* xch = xench; const u16* xcl = xencl;
    for (int l = 0; l < NL; l++){
      const float* Pa = (l == 0) ? P01g : P1g;
      const float* Pb = (l == 0) ? P02g : P2g;
      if (l == 0){
        chain_m8<1><<<NE/64, 256, 0, stream>>>(Pa, Pb, eag, senders,
            ea0, eW1, eb1, pe2h, pe2l, eb2,
            p1ch  + (size_t)l*S4B, p1cl  + (size_t)l*S4B, rmb1 + l*H,
            prm2h + (size_t)l*S4B, prm2l + (size_t)l*S4B, rmb2 + l*H,
            prm3h + (size_t)l*S4B, prm3l + (size_t)l*S4B, rmb3 + l*H,
            prm4h + (size_t)l*S4B, prm4l + (size_t)l*S4B, rmb4 + l*H);
      } else {
        chain_m8<0><<<NE/64, 256, 0, stream>>>(Pa, Pb, eag, senders,
            ea0, eW1, eb1, pe2h, pe2l, eb2,
            p1ch  + (size_t)l*S4B, p1cl  + (size_t)l*S4B, rmb1 + l*H,
            prm2h + (size_t)l*S4B, prm2l + (size_t)l*S4B, rmb2 + l*H,
            prm3h + (size_t)l*S4B, prm3l + (size_t)l*S4B, rmb3 + l*H,
            prm4h + (size_t)l*S4B, prm4l + (size_t)l*S4B, rmb4 + l*H);
      }
      u16* xnh = (l & 1) ? xAh : xBh;
      u16* xnl = (l & 1) ? xAl : xBl;
      int lp1 = (l < NL-1) ? (l+1) : l;
      objagg_m8<<<N_ATOMS/8, 256, 0, stream>>>(xch, xcl, eag, rowstart, elist,
          pom1h + (size_t)l*S8B, pom1l + (size_t)l*S8B, omb1 + l*H,
          pom2h + (size_t)l*S4B, pom2l + (size_t)l*S4B, omb2 + l*H,
          p1ah + (size_t)lp1*S4B, p1al + (size_t)lp1*S4B,
          p1bh + (size_t)lp1*S4B, p1bl + (size_t)lp1*S4B,
          xnh, xnl, P1g, P2g);
      xch = xnh; xcl = xnl;
    }
    decode_m8<<<N_ATOMS/16, 256, 0, stream>>>(xch, xcl, dW1, db1, dW2, db2, mass, posw, vels);
  }
  hipMemcpyAsync(d_out, posw, (size_t)N_ATOMS*3*4, hipMemcpyDeviceToDevice, stream);
}